// Round 4
// baseline (144.477 us; speedup 1.0000x reference)
//
#include <hip/hip_runtime.h>
#include <math.h>

#define EPSF 1e-8f

// native clang vectors — accepted by __builtin_nontemporal_load/store
typedef float nvec4 __attribute__((ext_vector_type(4)));
typedef int   nivec4 __attribute__((ext_vector_type(4)));

// Inclusive suffix scan of affine maps g(x)=A+Bx across the wave.
__device__ __forceinline__ void suffix_scan64(float& A, float& B, int lane) {
#pragma unroll
    for (int d = 1; d < 64; d <<= 1) {
        float Ao = __shfl_down(A, d);
        float Bo = __shfl_down(B, d);
        if (lane + d < 64) {
            A = fmaf(B, Ao, A);
            B = B * Bo;
        }
    }
}

// Round-0 structure (4 waves = 4 chunks of 256 per row, one barrier/row,
// 16B/lane coalesced) + 4-row persistence with 2-deep register prefetch,
// at FULL occupancy (__launch_bounds__(256,8): 8 blocks/CU, whole grid
// co-resident). r0 = blockIdx<<2 makes the values-alignment shift
// sh = (i+1)&3 a COMPILE-TIME constant per unrolled row: the sh-switch,
// tail pick() and clamp all fold away (sh!=0 tail is exactly t4.xyz;
// sh==0 needs no tail load). LDS stitch double-buffered by row parity.
// Block nb: sum_reward_weights on wave 0.
__global__ __launch_bounds__(256, 8)
void td_kernel(const float* __restrict__ raw_gamma,
               const float* __restrict__ raw_lambd, int lam_off,
               const float* __restrict__ values,
               const float* __restrict__ rewards,
               const int* __restrict__ dones,
               float* __restrict__ out, int B, int S)
{
    __shared__ float sA[2][4], sB[2][4];
    const int lane = threadIdx.x & 63;
    const int c    = threadIdx.x >> 6;        // chunk 0..3
    const int nb   = B >> 2;                  // main blocks (B % 4 == 0)
    const float gamma = fmaxf(tanhf(raw_gamma[0]), EPSF);

    if ((int)blockIdx.x == nb) {
        // ---- sum_reward_weights: wave 0, self-contained (round-0 code) ----
        if (threadIdx.x >= 64) return;
        const int base = lane << 4;           // 16 per lane over S=1024
        float a[16], b[16];
#pragma unroll
        for (int k = 0; k < 4; ++k) {
            float4 l4 = *(const float4*)(raw_lambd + lam_off + base + 4 * k);
            float lv[4] = {l4.x, l4.y, l4.z, l4.w};
#pragma unroll
            for (int j = 0; j < 4; ++j) {
                float g1 = gamma * fmaxf(tanhf(lv[j]), EPSF);
                b[4 * k + j] = g1;
                a[4 * k + j] = gamma - g1;
            }
        }
        float A = a[15], Bc = b[15];
#pragma unroll
        for (int j = 14; j >= 0; --j) { A = fmaf(b[j], A, a[j]); Bc *= b[j]; }
        suffix_scan64(A, Bc, lane);
        float EA = __shfl_down(A, 1);
        float EB = __shfl_down(Bc, 1);
        if (lane == 63) { EA = 0.0f; EB = 1.0f; }
        float v = EA + EB;                    // applied to v_next = 1.0
        float w[16], sum = 0.0f;
#pragma unroll
        for (int j = 15; j >= 0; --j) {
            v = fmaf(b[j], v, a[j]);
            w[j] = fmaxf(1.0f - v, EPSF);
            sum += w[j];
        }
#pragma unroll
        for (int d = 32; d; d >>= 1) sum += __shfl_xor(sum, d);
        float inv = 1.0f / fmaxf(sum / (float)S, EPSF);
        float* srw = out + (size_t)B * S;
#pragma unroll
        for (int j = 0; j < 16; ++j) srw[base + j] = w[j] * inv;
        return;
    }

    // ---- lambda_returns: 4 rows per block, 2-deep register prefetch ----
    const int C  = S >> 2;                    // 256
    const int t0 = c * C + (lane << 2);

    // λ coefficients: identical for all 4 rows — hoisted.
    float4 l4 = *(const float4*)(raw_lambd + lam_off + t0);
    float lv[4] = {l4.x, l4.y, l4.z, l4.w};
    float g1v[4], av[4];
#pragma unroll
    for (int j = 0; j < 4; ++j) {
        g1v[j] = gamma * fmaxf(tanhf(lv[j]), EPSF);
        av[j]  = gamma - g1v[j];
    }

    const int r0 = (int)blockIdx.x << 2;      // rows r0..r0+3

    // double-buffered per-row stream state
    nvec4  r4[2]; nivec4 d4[2]; nvec4 m4[2], t4[2]; float vS[2];

    // RI is a compile-time constant in the unrolled loop: _sh folds, the
    // tail load is skipped for _sh==0, and no clamp/pick/dlt is needed
    // (for _sh!=0, rows are r%4 != 3 so r <= B-2 and A0+259 stays in the
    // values array — it reads the start of row r+1's region, valid memory).
#define ISSUE(BUF, RI) do {                                                     \
        const int _r = r0 + (RI);                                               \
        const int _sh = ((RI) + 1) & 3;                                         \
        r4[BUF] = __builtin_nontemporal_load(                                   \
            (const nvec4*)(rewards + (size_t)_r * S + t0));                     \
        d4[BUF] = __builtin_nontemporal_load(                                   \
            (const nivec4*)(dones + (size_t)_r * S + t0));                      \
        const size_t _rb = (size_t)_r * (S + 1);                                \
        const size_t _A0 = _rb + (size_t)c * C + 1 - _sh;                       \
        m4[BUF] = __builtin_nontemporal_load((const nvec4*)(values + _A0) + lane); \
        if (_sh != 0)                                                           \
            t4[BUF] = __builtin_nontemporal_load((const nvec4*)(values + _A0 + 256)); \
        vS[BUF] = values[_rb + S];                                              \
    } while (0)

    ISSUE(0, 0);                              // prologue

#pragma unroll
    for (int i = 0; i < 4; ++i) {
        const int cur = i & 1;
        const int SH  = (i + 1) & 3;          // compile-time per iteration
        const int r   = r0 + i;
        if (i < 3) ISSUE(cur ^ 1, i + 1);     // prefetch next row NOW

        // Reconstruct v_{t+1}..v_{t+4} from the aligned cover.
        float vn0, vn1, vn2, vn3;
        if (SH == 0) {
            vn0 = m4[cur].x; vn1 = m4[cur].y; vn2 = m4[cur].z; vn3 = m4[cur].w;
        } else {
            float n0 = __shfl_down(m4[cur].x, 1);
            float n1 = __shfl_down(m4[cur].y, 1);
            float n2 = __shfl_down(m4[cur].z, 1);
            if (lane == 63) { n0 = t4[cur].x; n1 = t4[cur].y; n2 = t4[cur].z; }
            if (SH == 1)      { vn0 = m4[cur].y; vn1 = m4[cur].z; vn2 = m4[cur].w; vn3 = n0; }
            else if (SH == 2) { vn0 = m4[cur].z; vn1 = m4[cur].w; vn2 = n0;        vn3 = n1; }
            else              { vn0 = m4[cur].w; vn1 = n0;        vn2 = n1;        vn3 = n2; }
        }

        // Affine coefficients: ret_t = a_t + b_t * ret_{t+1}
        float vn[4] = {vn0, vn1, vn2, vn3};
        float rr[4] = {r4[cur].x, r4[cur].y, r4[cur].z, r4[cur].w};
        int   di[4] = {d4[cur].x, d4[cur].y, d4[cur].z, d4[cur].w};
        float a[4], b[4];
#pragma unroll
        for (int j = 0; j < 4; ++j) {
            float ndn = 1.0f - (float)di[j];
            b[j] = g1v[j] * ndn;
            a[j] = fmaf(av[j] * vn[j], ndn, rr[j]);
        }

        // Lane-local composite of 4 maps, then one 64-lane suffix scan.
        float A = a[3], Bc = b[3];
#pragma unroll
        for (int j = 2; j >= 0; --j) { A = fmaf(b[j], A, a[j]); Bc *= b[j]; }
        suffix_scan64(A, Bc, lane);
        float EA = __shfl_down(A, 1);
        float EB = __shfl_down(Bc, 1);
        if (lane == 63) { EA = 0.0f; EB = 1.0f; }
        if (lane == 0) { sA[cur][c] = A; sB[cur][c] = Bc; }
        __syncthreads();                      // one barrier per row

        // Carry into this chunk: apply later chunks' composites to v_S.
        float x = vS[cur];
#pragma unroll
        for (int j = 3; j >= 1; --j)
            if (j > c) x = fmaf(sB[cur][j], x, sA[cur][j]);  // block-uniform per wave

        float xi = fmaf(EB, x, EA);           // ret at t0+4
        float o3 = fmaf(b[3], xi, a[3]);
        float o2 = fmaf(b[2], o3, a[2]);
        float o1 = fmaf(b[1], o2, a[1]);
        float o0 = fmaf(b[0], o1, a[0]);
        nvec4 ov = {o0, o1, o2, o3};
        __builtin_nontemporal_store(ov, (nvec4*)(out + (size_t)r * S + t0));
    }
#undef ISSUE
}

extern "C" void kernel_launch(void* const* d_in, const int* in_sizes, int n_in,
                              void* d_out, int out_size, void* d_ws, size_t ws_size,
                              hipStream_t stream) {
    const float* raw_gamma = (const float*)d_in[0];
    const float* raw_lambd = (const float*)d_in[1];
    const float* values    = (const float*)d_in[2];
    const float* rewards   = (const float*)d_in[3];
    const int*   dones     = (const int*)d_in[4];
    float* out = (float*)d_out;

    int n_v = in_sizes[2];           // B*(S+1)
    int n_r = in_sizes[3];           // B*S
    int B = n_v - n_r;               // 8192
    int S = n_r / B;                 // 1024
    int lam_off = in_sizes[1] - S;

    int nb = B >> 2;                 // 4 rows per block, whole grid co-resident
    td_kernel<<<nb + 1, 256, 0, stream>>>(
        raw_gamma, raw_lambd, lam_off, values, rewards, dones, out, B, S);
}

// Round 5
// 138.728 us; speedup vs baseline: 1.0414x; 1.0414x over previous
//
#include <hip/hip_runtime.h>
#include <math.h>

#define EPSF 1e-8f

// native clang vectors — accepted by __builtin_nontemporal_load/store
typedef float nvec4 __attribute__((ext_vector_type(4)));
typedef int   nivec4 __attribute__((ext_vector_type(4)));

__device__ __forceinline__ float pick(nvec4 v, int i) {
    return i == 0 ? v.x : i == 1 ? v.y : i == 2 ? v.z : v.w;
}

// Inclusive suffix scan of affine maps g(x)=A+Bx across the wave.
__device__ __forceinline__ void suffix_scan64(float& A, float& B, int lane) {
#pragma unroll
    for (int d = 1; d < 64; d <<= 1) {
        float Ao = __shfl_down(A, d);
        float Bo = __shfl_down(B, d);
        if (lane + d < 64) {
            A = fmaf(B, Ao, A);
            B = B * Bo;
        }
    }
}

// Single fused kernel. Block r < B: one row, 4 waves = 4 chunks of 256,
// stitched through an 8-float LDS exchange + one barrier. No λ-table:
// each lane tanh's only its own 4 λ values. values stream goes through an
// ALIGNED 16B cover (row base ≡ r mod 4 elements) + shuffle reconstruct.
// Block r == B: sum_reward_weights on wave 0 (no LDS, no barrier).
//
// Session verdict (rounds 0-4): this structure is the empirical optimum.
//   R1 split-prep (tanh removal): neutral kernel-side, +5us launch  -> VALU hidden
//   R2 wave-per-row: td=50.7us @ 2.3TB/s                            -> latency-bound
//   R3/R4 persistent-4-row + reg prefetch (occ 4 and 8): +2..+5us   -> regressed
// td phase ~28us = 134MB @ ~4.8TB/s (~76% of achievable streaming BW).
__global__ __launch_bounds__(256, 8)
void td_kernel(const float* __restrict__ raw_gamma,
               const float* __restrict__ raw_lambd, int lam_off,
               const float* __restrict__ values,
               const float* __restrict__ rewards,
               const int* __restrict__ dones,
               float* __restrict__ out, int B, int S)
{
    __shared__ float sA[4], sB[4];
    const int lane = threadIdx.x & 63;
    const int c    = threadIdx.x >> 6;        // chunk 0..3
    const float gamma = fmaxf(tanhf(raw_gamma[0]), EPSF);

    if ((int)blockIdx.x == B) {
        // ---- sum_reward_weights: wave 0, self-contained ----
        if (threadIdx.x >= 64) return;
        const int base = lane << 4;           // 16 per lane over S=1024
        float a[16], b[16];
#pragma unroll
        for (int k = 0; k < 4; ++k) {
            float4 l4 = *(const float4*)(raw_lambd + lam_off + base + 4 * k);
            float lv[4] = {l4.x, l4.y, l4.z, l4.w};
#pragma unroll
            for (int j = 0; j < 4; ++j) {
                float g1 = gamma * fmaxf(tanhf(lv[j]), EPSF);
                b[4 * k + j] = g1;
                a[4 * k + j] = gamma - g1;
            }
        }
        float A = a[15], Bc = b[15];
#pragma unroll
        for (int j = 14; j >= 0; --j) { A = fmaf(b[j], A, a[j]); Bc *= b[j]; }
        suffix_scan64(A, Bc, lane);
        float EA = __shfl_down(A, 1);
        float EB = __shfl_down(Bc, 1);
        if (lane == 63) { EA = 0.0f; EB = 1.0f; }
        float v = EA + EB;                    // applied to v_next = 1.0
        float w[16], sum = 0.0f;
#pragma unroll
        for (int j = 15; j >= 0; --j) {
            v = fmaf(b[j], v, a[j]);
            w[j] = fmaxf(1.0f - v, EPSF);
            sum += w[j];
        }
#pragma unroll
        for (int d = 32; d; d >>= 1) sum += __shfl_xor(sum, d);
        float inv = 1.0f / fmaxf(sum / (float)S, EPSF);
        float* srw = out + (size_t)B * S;
#pragma unroll
        for (int j = 0; j < 16; ++j) srw[base + j] = w[j] * inv;
        return;
    }

    // ---- lambda_returns ----
    const int r  = blockIdx.x;
    const int C  = S >> 2;                    // 256
    const int t0 = c * C + (lane << 2);
    const size_t rb = (size_t)r * (S + 1);

    // Issue all stream loads up-front (coalesced, nontemporal).
    nvec4  r4 = __builtin_nontemporal_load((const nvec4*)(rewards + (size_t)r * S + t0));
    nivec4 d4 = __builtin_nontemporal_load((const nivec4*)(dones + (size_t)r * S + t0));

    const int sh = (r + 1) & 3;               // (rb + c*C + 1) & 3, block-uniform
    const size_t E  = rb + (size_t)c * C + 1; // first needed v element
    const size_t A0 = E - sh;                 // 16B-aligned cover start
    nvec4 m4 = __builtin_nontemporal_load((const nvec4*)(values + A0) + lane);
    size_t A0t = A0 + 256;                    // tail (4 elems past cover)
    const size_t last4 = (size_t)B * (S + 1) - 4;
    if (A0t > last4) A0t = last4;             // clamp (only hits on last row, sh=0)
    nvec4 t4 = __builtin_nontemporal_load((const nvec4*)(values + A0t));
    const int delta = (int)(A0 + 256 - A0t);
    float vS = values[rb + S];

    // λ coefficients: each lane tanh's only its 4 values (aligned float4).
    float4 l4 = *(const float4*)(raw_lambd + lam_off + t0);
    float lv[4] = {l4.x, l4.y, l4.z, l4.w};
    float g1v[4];
#pragma unroll
    for (int j = 0; j < 4; ++j)
        g1v[j] = gamma * fmaxf(tanhf(lv[j]), EPSF);

    // Reconstruct v_{t+1}..v_{t+4} from the aligned cover.
    float n0 = __shfl_down(m4.x, 1);
    float n1 = __shfl_down(m4.y, 1);
    float n2 = __shfl_down(m4.z, 1);
    if (lane == 63) {
        n0 = pick(t4, delta);
        n1 = pick(t4, delta + 1 > 3 ? 3 : delta + 1);
        n2 = pick(t4, delta + 2 > 3 ? 3 : delta + 2);
    }
    float vn0, vn1, vn2, vn3;
    if (sh == 0)      { vn0 = m4.x; vn1 = m4.y; vn2 = m4.z; vn3 = m4.w; }
    else if (sh == 1) { vn0 = m4.y; vn1 = m4.z; vn2 = m4.w; vn3 = n0; }
    else if (sh == 2) { vn0 = m4.z; vn1 = m4.w; vn2 = n0;   vn3 = n1; }
    else              { vn0 = m4.w; vn1 = n0;   vn2 = n1;   vn3 = n2; }

    // Affine coefficients: ret_t = a_t + b_t * ret_{t+1}
    float vn[4] = {vn0, vn1, vn2, vn3};
    float rr[4] = {r4.x, r4.y, r4.z, r4.w};
    int   di[4] = {d4.x, d4.y, d4.z, d4.w};
    float a[4], b[4];
#pragma unroll
    for (int j = 0; j < 4; ++j) {
        float ndn = 1.0f - (float)di[j];
        b[j] = g1v[j] * ndn;
        a[j] = fmaf((gamma - g1v[j]) * vn[j], ndn, rr[j]);
    }

    // Lane-local composite of 4 maps, then one 64-lane suffix scan.
    float A = a[3], Bc = b[3];
#pragma unroll
    for (int j = 2; j >= 0; --j) { A = fmaf(b[j], A, a[j]); Bc *= b[j]; }
    suffix_scan64(A, Bc, lane);
    float EA = __shfl_down(A, 1);
    float EB = __shfl_down(Bc, 1);
    if (lane == 63) { EA = 0.0f; EB = 1.0f; }
    if (lane == 0) { sA[c] = A; sB[c] = Bc; }
    __syncthreads();

    // Carry into this chunk: apply later chunks' composites to v_S.
    float x = vS;
#pragma unroll
    for (int j = 3; j >= 1; --j)
        if (j > c) x = fmaf(sB[j], x, sA[j]);   // block-uniform per wave

    float xi = fmaf(EB, x, EA);                 // ret at t0+4
    float o3 = fmaf(b[3], xi, a[3]);
    float o2 = fmaf(b[2], o3, a[2]);
    float o1 = fmaf(b[1], o2, a[1]);
    float o0 = fmaf(b[0], o1, a[0]);
    nvec4 ov = {o0, o1, o2, o3};
    __builtin_nontemporal_store(ov, (nvec4*)(out + (size_t)r * S + t0));
}

extern "C" void kernel_launch(void* const* d_in, const int* in_sizes, int n_in,
                              void* d_out, int out_size, void* d_ws, size_t ws_size,
                              hipStream_t stream) {
    const float* raw_gamma = (const float*)d_in[0];
    const float* raw_lambd = (const float*)d_in[1];
    const float* values    = (const float*)d_in[2];
    const float* rewards   = (const float*)d_in[3];
    const int*   dones     = (const int*)d_in[4];
    float* out = (float*)d_out;

    int n_v = in_sizes[2];           // B*(S+1)
    int n_r = in_sizes[3];           // B*S
    int B = n_v - n_r;               // 8192
    int S = n_r / B;                 // 1024
    int lam_off = in_sizes[1] - S;

    td_kernel<<<B + 1, 256, 0, stream>>>(
        raw_gamma, raw_lambd, lam_off, values, rewards, dones, out, B, S);
}